// Round 1
// baseline (95.717 us; speedup 1.0000x reference)
//
#include <hip/hip_runtime.h>
#include <math.h>

// EngryEncoder: per-frame RMS over reflect-padded signal.
// signal: (16, 1048576) f32; pad=512 reflect; frames: 4096 per batch,
// hop=256, win=1024. out[b][f] = sqrt(mean(x[b, f*256 : f*256+1024]^2))
// over the PADDED signal x.
//
// Decomposition: block sums of squares at hop granularity (256 samples),
// frame f = blocks f..f+3. One WG = 64 frames = 67 blocks, 4.7% redundancy.

#define NFFT    1024
#define HOPSZ   256
#define PADSZ   512
#define SIGLEN  1048576
#define FRAMES  4096            // per batch
#define F_PER_WG 64
#define BLOCKS_PER_WG (F_PER_WG + 3)    // 67
#define WG_PER_BATCH (FRAMES / F_PER_WG) // 64

__global__ __launch_bounds__(256) void energy_kernel(
    const float* __restrict__ sig, float* __restrict__ out)
{
    const int wg  = blockIdx.x;
    const int b   = wg / WG_PER_BATCH;
    const int seg = wg % WG_PER_BATCH;
    const int f0  = seg * F_PER_WG;
    const float* __restrict__ s = sig + (size_t)b * SIGLEN;

    __shared__ float bsum[BLOCKS_PER_WG];

    const int tid  = threadIdx.x;
    const int lane = tid & 63;
    const int wave = tid >> 6;

    // Each wave handles blocks j = wave, wave+4, ... (<67).
    for (int j = wave; j < BLOCKS_PER_WG; j += 4) {
        const int p = (f0 + j) * HOPSZ + lane * 4;  // padded index of first elem
        const int i = p - PADSZ;                    // original index
        float v0, v1, v2, v3;
        if (i >= 0 && i + 3 < SIGLEN) {
            // interior: aligned coalesced float4 (i is a multiple of 4)
            const float4 v = *reinterpret_cast<const float4*>(s + i);
            v0 = v.x; v1 = v.y; v2 = v.z; v3 = v.w;
        } else {
            // reflect boundary (only first/last WG of each batch hits this)
            auto refl = [&](int k) -> float {
                if (k < 0) k = -k;
                if (k >= SIGLEN) k = 2 * SIGLEN - 2 - k;
                return s[k];
            };
            v0 = refl(i); v1 = refl(i + 1); v2 = refl(i + 2); v3 = refl(i + 3);
        }
        float acc = v0 * v0 + v1 * v1 + v2 * v2 + v3 * v3;
        // wave64 butterfly reduce
        #pragma unroll
        for (int off = 32; off > 0; off >>= 1)
            acc += __shfl_xor(acc, off, 64);
        if (lane == 0) bsum[j] = acc;
    }
    __syncthreads();

    if (tid < F_PER_WG) {
        const float sum = bsum[tid] + bsum[tid + 1] + bsum[tid + 2] + bsum[tid + 3];
        out[(size_t)b * FRAMES + f0 + tid] = sqrtf(sum * (1.0f / NFFT));
    }
}

extern "C" void kernel_launch(void* const* d_in, const int* in_sizes, int n_in,
                              void* d_out, int out_size, void* d_ws, size_t ws_size,
                              hipStream_t stream)
{
    const float* sig = (const float*)d_in[0];
    float* out = (float*)d_out;
    const int grid = 16 * WG_PER_BATCH;  // 1024 workgroups
    energy_kernel<<<grid, 256, 0, stream>>>(sig, out);
}

// Round 2
// 93.303 us; speedup vs baseline: 1.0259x; 1.0259x over previous
//
#include <hip/hip_runtime.h>
#include <math.h>

// EngryEncoder: per-frame RMS over reflect-padded signal.
// signal: (16, 1048576) f32; pad=512 reflect; 4096 frames/batch, hop=256,
// win=1024. out[b][f] = sqrt(mean over 1024 padded samples starting f*256).
//
// Frame f = hop-blocks f..f+3 (block = 256-sample sumsq).
// pad (512) == 2*hop, so reflect blocks are FULL mirrored blocks, and sumsq
// is permutation-invariant -> blocks 0,1,4098 are contiguous-range sumsqs:
//   blk 0 -> s[257..512], blk 1 -> s[1..256], blk 4098 -> s[1048319..1048574].
//
// Hot loop = pure streaming: per-lane float4 sumsq -> LDS[blk][lane].
// No cross-lane ops until the one-time final reduce.

#define NFFT    1024
#define HOPSZ   256
#define PADSZ   512
#define SIGLEN  1048576
#define FRAMES  4096
#define F_PER_WG 64
#define BLOCKS_PER_WG (F_PER_WG + 3)      // 67
#define WG_PER_BATCH (FRAMES / F_PER_WG)  // 64
#define LDS_STRIDE 65                     // pad 64 -> 65 (conflict-free row sums)

__global__ __launch_bounds__(256) void energy_kernel(
    const float* __restrict__ sig, float* __restrict__ out)
{
    const int wg  = blockIdx.x;
    const int b   = wg / WG_PER_BATCH;
    const int seg = wg % WG_PER_BATCH;
    const int f0  = seg * F_PER_WG;
    const float* __restrict__ s = sig + (size_t)b * SIGLEN;

    __shared__ float part[BLOCKS_PER_WG * LDS_STRIDE];  // 17.4 KB

    const int tid  = threadIdx.x;
    const int lane = tid & 63;
    const int wave = tid >> 6;

    // Hot loop: waves interleave over 67 blocks; all loads independent.
    #pragma unroll
    for (int it = 0; it < 17; ++it) {
        const int j = wave + it * 4;
        if (j < BLOCKS_PER_WG) {
            const int blk = f0 + j;
            float acc;
            if (blk >= 2 && blk < 4098) {
                // interior: aligned coalesced float4
                const float4 v = *reinterpret_cast<const float4*>(
                    s + blk * HOPSZ - PADSZ + lane * 4);
                acc = v.x * v.x + v.y * v.y + v.z * v.z + v.w * v.w;
            } else {
                // full-reflect block == contiguous range, unaligned base
                const int base = (blk == 0) ? 257 : (blk == 1) ? 1 : (SIGLEN - 257);
                const float* p = s + base + lane * 4;
                acc = p[0] * p[0] + p[1] * p[1] + p[2] * p[2] + p[3] * p[3];
            }
            part[j * LDS_STRIDE + lane] = acc;  // bank = (j+lane)%32: 2-way, free
        }
    }
    __syncthreads();

    // Final reduce: 4 threads per frame, each sums one LDS row (64 floats).
    const int f = tid >> 2;   // 0..63 local frame
    const int q = tid & 3;    // which of the 4 blocks
    const int r = f + q;      // LDS row 0..66
    float sum = 0.f;
    #pragma unroll 8
    for (int k = 0; k < 64; ++k)
        sum += part[r * LDS_STRIDE + k];
    // combine the 4 per-block partials (threads t, t^1, t^2, t^3 share f)
    sum += __shfl_xor(sum, 1, 64);
    sum += __shfl_xor(sum, 2, 64);
    if (q == 0)
        out[(size_t)b * FRAMES + f0 + f] = sqrtf(sum * (1.0f / NFFT));
}

extern "C" void kernel_launch(void* const* d_in, const int* in_sizes, int n_in,
                              void* d_out, int out_size, void* d_ws, size_t ws_size,
                              hipStream_t stream)
{
    const float* sig = (const float*)d_in[0];
    float* out = (float*)d_out;
    const int grid = 16 * WG_PER_BATCH;  // 1024 workgroups, 4/CU, 16 waves/CU
    energy_kernel<<<grid, 256, 0, stream>>>(sig, out);
}

// Round 3
// 92.552 us; speedup vs baseline: 1.0342x; 1.0081x over previous
//
#include <hip/hip_runtime.h>
#include <math.h>

// EngryEncoder: per-frame RMS over reflect-padded signal.
// signal: (16, 1048576) f32; pad=512 reflect; 4096 frames/batch, hop=256,
// win=1024. Frame f = hop-blocks f..f+3 (block = 256-sample sumsq).
// pad == 2*hop, so reflect blocks are full mirrored blocks; sumsq is
// permutation-invariant -> blocks 0,1,4098 are contiguous-range sumsqs.
//
// Hot loop: pure streaming, per-lane float4 sumsq -> LDS[blk][lane].
// Tail: balanced two-stage reduce (quarter-rows -> row totals -> frames).

#define NFFT    1024
#define HOPSZ   256
#define PADSZ   512
#define SIGLEN  1048576
#define FRAMES  4096
#define F_PER_WG 64
#define BLOCKS_PER_WG (F_PER_WG + 3)      // 67
#define WG_PER_BATCH (FRAMES / F_PER_WG)  // 64
#define LDS_STRIDE 65                     // conflict-free quarter-row reads

__global__ __launch_bounds__(256) void energy_kernel(
    const float* __restrict__ sig, float* __restrict__ out)
{
    const int wg  = blockIdx.x;
    const int b   = wg / WG_PER_BATCH;
    const int seg = wg % WG_PER_BATCH;
    const int f0  = seg * F_PER_WG;
    const float* __restrict__ s = sig + (size_t)b * SIGLEN;

    __shared__ float part[BLOCKS_PER_WG * LDS_STRIDE];  // 17.4 KB
    __shared__ float rowtot[BLOCKS_PER_WG];

    const int tid  = threadIdx.x;
    const int lane = tid & 63;
    const int wave = tid >> 6;

    // Hot loop: waves interleave over 67 blocks; all 17 loads independent.
    #pragma unroll
    for (int it = 0; it < 17; ++it) {
        const int j = wave + it * 4;
        if (j < BLOCKS_PER_WG) {
            const int blk = f0 + j;
            float acc;
            if (blk >= 2 && blk < 4098) {
                const float4 v = *reinterpret_cast<const float4*>(
                    s + blk * HOPSZ - PADSZ + lane * 4);
                acc = v.x * v.x + v.y * v.y + v.z * v.z + v.w * v.w;
            } else {
                // full-reflect block == contiguous range (unaligned base)
                const int base = (blk == 0) ? 257 : (blk == 1) ? 1 : (SIGLEN - 257);
                const float* p = s + base + lane * 4;
                acc = p[0] * p[0] + p[1] * p[1] + p[2] * p[2] + p[3] * p[3];
            }
            part[j * LDS_STRIDE + lane] = acc;  // banks (j+lane)%32: 2-way, free
        }
    }
    __syncthreads();

    // Stage A: 4 threads per row, each sums a 16-elem quarter-row.
    {
        const int r = tid >> 2;          // row 0..63
        const int q = tid & 3;           // quarter
        const float* rp = &part[r * LDS_STRIDE + q * 16];
        float s1 = 0.f;
        #pragma unroll
        for (int k = 0; k < 16; ++k) s1 += rp[k];
        s1 += __shfl_xor(s1, 1, 64);
        s1 += __shfl_xor(s1, 2, 64);
        if (q == 0) rowtot[r] = s1;
    }
    // Rows 64..66 by threads 0..11 (partners within lanes 0..11, same wave).
    if (tid < 12) {
        const int r2 = 64 + (tid >> 2);
        const int q2 = tid & 3;
        const float* rp = &part[r2 * LDS_STRIDE + q2 * 16];
        float s2 = 0.f;
        #pragma unroll
        for (int k = 0; k < 16; ++k) s2 += rp[k];
        s2 += __shfl_xor(s2, 1, 64);
        s2 += __shfl_xor(s2, 2, 64);
        if (q2 == 0) rowtot[r2] = s2;
    }
    __syncthreads();

    // Stage B: frame f = rows f..f+3.
    if (tid < F_PER_WG) {
        const float sum = rowtot[tid] + rowtot[tid + 1]
                        + rowtot[tid + 2] + rowtot[tid + 3];
        out[(size_t)b * FRAMES + f0 + tid] = sqrtf(sum * (1.0f / NFFT));
    }
}

extern "C" void kernel_launch(void* const* d_in, const int* in_sizes, int n_in,
                              void* d_out, int out_size, void* d_ws, size_t ws_size,
                              hipStream_t stream)
{
    const float* sig = (const float*)d_in[0];
    float* out = (float*)d_out;
    const int grid = 16 * WG_PER_BATCH;  // 1024 workgroups
    energy_kernel<<<grid, 256, 0, stream>>>(sig, out);
}